// Round 4
// baseline (1843.126 us; speedup 1.0000x reference)
//
#include <hip/hip_runtime.h>
#include <hip/hip_bf16.h>

// CharNNClassifier: out = (LSTM(emb[x]) last h) @ W_out^T + b_out
// B=256 S=512 V=256 E=128 H=256 4H=1024 O=128, fp32 in/out.
//
// R4 design (R3 + wave desync):
//  - 16 wgs x 512 threads, W_hh fp16 frags split: kt 0..1 in LDS (128 KB),
//    kt 2..7 in VGPRs (192/lane).
//  - NO per-step __syncthreads. Per-wave monotonic progress flags in LDS
//    (prog[wv] = 2s+1+p after storing h half p of step s, release/acquire,
//    workgroup scope). Consumers wait per k-tile on its 2 producer waves.
//    => wave A's MFMAs overlap wave B's epilogue VALU.
//  - Step split into 2 gate-parity passes (j = 2g+p): only 4 accs live
//    (16 regs) => total live ~250 <= 256 budget, no spill.
//  - T2h (fp16x4 gate table) prefetched before each MFMA pass.

typedef _Float16 f16x8 __attribute__((ext_vector_type(8)));
typedef _Float16 f16x4 __attribute__((ext_vector_type(4)));
typedef float    f32x4 __attribute__((ext_vector_type(4)));

#define B_  256
#define S_  512
#define V_  256
#define E_  128
#define H_  256
#define O_  128

// ws layout (bytes)
#define T_OFF     0u              // T2h: 256*256*4 fp16 = 512 KiB
#define HLAST_OFF (1u << 19)      // hlast: 256*256*4B = 256 KiB

// ---------------------------------------------------------------- K1: table
// T2h[v][unit] = fp16x4 {i,f,g,o} pre-activations from the embedding path.
__global__ void build_table(const float* __restrict__ emb,
                            const float* __restrict__ W_ih,
                            const float* __restrict__ b_ih,
                            const float* __restrict__ b_hh,
                            _Float16* __restrict__ T2h) {
    const int v   = blockIdx.x;   // vocab id
    const int tid = threadIdx.x;  // 256 threads = hidden unit

    __shared__ float e[E_];
    if (tid < E_) e[tid] = emb[v * E_ + tid];
    __syncthreads();

    f16x4 tv;
#pragma unroll
    for (int t = 0; t < 4; ++t) {
        const int g = t * 256 + tid;
        const float4* wp = (const float4*)(W_ih + g * E_);
        float acc = 0.f;
#pragma unroll
        for (int i = 0; i < E_ / 4; ++i) {
            float4 w = wp[i];
            acc += w.x * e[4*i] + w.y * e[4*i+1] + w.z * e[4*i+2] + w.w * e[4*i+3];
        }
        tv[t] = (_Float16)(acc + b_ih[g] + b_hh[g]);
    }
    *(f16x4*)(T2h + ((size_t)v * 256 + tid) * 4) = tv;
}

// ------------------------------------------------------------ K2: recurrence
__device__ __forceinline__ float sig_fast(float x) {
    x = fminf(fmaxf(x, -30.f), 30.f);
    float t = __builtin_amdgcn_exp2f(-1.4426950408889634f * x);
    return __builtin_amdgcn_rcpf(1.f + t);
}
__device__ __forceinline__ float tanh_fast(float x) {
    x = fminf(fmaxf(x, -15.f), 15.f);
    float t = __builtin_amdgcn_exp2f(-2.8853900817779268f * x);  // e^{-2x}
    return (1.f - t) * __builtin_amdgcn_rcpf(1.f + t);
}

#define HSTRIDE 264   // fp16 per LDS h row: 256 + 8 pad

__launch_bounds__(512, 2)
__global__ void lstm_persistent(const int* __restrict__ x,
                                const float* __restrict__ W_hh,
                                const _Float16* __restrict__ T2h,
                                float* __restrict__ hlast) {
    const int tid    = threadIdx.x;
    const int wv     = tid >> 6;     // wave 0..7
    const int l      = tid & 63;
    const int l15    = l & 15;
    const int quad   = l >> 4;       // 0..3
    const int stripe = blockIdx.x;   // batch rows [stripe*16, +16)

    // LDS: 128 KB weights (kt 0..1) + h dbuf (16.5 KB) + flags.
    __shared__ __align__(16) _Float16 wlds[8][8][2][512];
    __shared__ __align__(16) _Float16 hbuf[2][16][HSTRIDE];
    __shared__ __align__(16) int prog[8];

    // ---- prologue: W_hh -> fp16 MFMA B-fragments.
    // col n = j*128 + wv*16 + l15; k = kt*32 + quad*8 + i; B[k][n]=W_hh[n][k].
    f16x8 wreg[8][6];
#pragma unroll
    for (int j = 0; j < 8; ++j) {
        const float* wr = W_hh + (j * 128 + wv * 16 + l15) * H_ + quad * 8;
#pragma unroll
        for (int kt = 0; kt < 8; ++kt) {
            const float4* wp = (const float4*)(wr + kt * 32);
            float4 w0 = wp[0];
            float4 w1 = wp[1];
            f16x8 f = (f16x8){
                (_Float16)w0.x, (_Float16)w0.y, (_Float16)w0.z, (_Float16)w0.w,
                (_Float16)w1.x, (_Float16)w1.y, (_Float16)w1.z, (_Float16)w1.w};
            if (kt < 2)
                *(f16x8*)&wlds[wv][j][kt][(size_t)l * 8] = f;
            else
                wreg[j][kt - 2] = f;
        }
    }
    if (l == 0) prog[wv] = 0;
    __syncthreads();   // only barrier in the kernel body

    float c[2][4] = {{0.f, 0.f, 0.f, 0.f}, {0.f, 0.f, 0.f, 0.f}};
    const int row0 = stripe * 16 + quad * 4;   // this lane's 4 C-rows
    const int u0   = wv * 16 + l15;            // hidden unit, p=0 half

    for (int s = 0; s < S_; ++s) {
        // x indices for this lane's 4 rows (L1-resident)
        int vv[4];
#pragma unroll
        for (int r = 0; r < 4; ++r) vv[r] = x[(row0 + r) * S_ + s];

#pragma unroll
        for (int p = 0; p < 2; ++p) {
            const int u = u0 + p * 128;

            // prefetch gate table for this half: latency hides under MFMAs
            f16x4 tv[4];
#pragma unroll
            for (int r = 0; r < 4; ++r)
                tv[r] = *(const f16x4*)(T2h + ((size_t)vv[r] * 256 + u) * 4);

            f32x4 acc4[4];
#pragma unroll
            for (int g = 0; g < 4; ++g) acc4[g] = (f32x4){0.f, 0.f, 0.f, 0.f};

            if (s > 0) {
                const _Float16* hb =
                    &hbuf[(s - 1) & 1][0][0] + l15 * HSTRIDE + quad * 8;
#pragma unroll
                for (int kt = 0; kt < 8; ++kt) {
                    if (p == 0) {
                        // wait for the 2 producer waves of k-tile kt of h_{s-1}
                        const int k0 = kt & 3;
                        const int th = 2 * s - 1 + (kt >> 2);
                        const long long* fp = (const long long*)&prog[2 * k0];
                        for (;;) {
                            long long v = __hip_atomic_load(
                                fp, __ATOMIC_ACQUIRE, __HIP_MEMORY_SCOPE_WORKGROUP);
                            if ((int)v >= th && (int)(v >> 32) >= th) break;
                        }
                    }   // p==1: all tiles proven ready during p==0 pass
                    f16x8 a = *(const f16x8*)(hb + kt * 32);
#pragma unroll
                    for (int g = 0; g < 4; ++g) {
                        if (kt < 2) {
                            f16x8 b = *(const f16x8*)
                                &wlds[wv][2 * g + p][kt][(size_t)l * 8];
                            acc4[g] = __builtin_amdgcn_mfma_f32_16x16x32_f16(
                                a, b, acc4[g], 0, 0, 0);
                        } else {
                            acc4[g] = __builtin_amdgcn_mfma_f32_16x16x32_f16(
                                a, wreg[2 * g + p][kt - 2], acc4[g], 0, 0, 0);
                        }
                    }
                }
            }

            // epilogue for half p. C/D layout: col=l15, row=quad*4+r.
#pragma unroll
            for (int r = 0; r < 4; ++r) {
                float gi = sig_fast (acc4[0][r] + (float)tv[r][0]);
                float gf = sig_fast (acc4[1][r] + (float)tv[r][1]);
                float gg = tanh_fast(acc4[2][r] + (float)tv[r][2]);
                float go = sig_fast (acc4[3][r] + (float)tv[r][3]);
                float cc = gf * c[p][r] + gi * gg;
                c[p][r]  = cc;
                float hv = go * tanh_fast(cc);
                if (s < S_ - 1) {
                    hbuf[s & 1][quad * 4 + r][u] = (_Float16)hv;
                } else {
                    hlast[(row0 + r) * H_ + u] = hv;   // fp32 for the head
                }
            }
            if (s < S_ - 1) {
                // publish: release orders the ds_writes above before the flag
                if (l == 0)
                    __hip_atomic_store(&prog[wv], 2 * s + 1 + p,
                                       __ATOMIC_RELEASE,
                                       __HIP_MEMORY_SCOPE_WORKGROUP);
            }
        }
    }
}

// ---------------------------------------------------------------- K3: head
__global__ void out_kernel(const float* __restrict__ hlast,
                           const float* __restrict__ W_out,
                           const float* __restrict__ b_out,
                           float* __restrict__ out) {
    const int b = blockIdx.x;    // 256
    const int o = threadIdx.x;   // 128
    __shared__ float hl[H_];
    hl[o]       = hlast[b * H_ + o];
    hl[o + 128] = hlast[b * H_ + o + 128];
    __syncthreads();
    const float4* wp = (const float4*)(W_out + o * H_);
    float acc = 0.f;
#pragma unroll
    for (int i = 0; i < H_ / 4; ++i) {
        float4 w = wp[i];
        acc += w.x * hl[4*i] + w.y * hl[4*i+1] + w.z * hl[4*i+2] + w.w * hl[4*i+3];
    }
    out[b * O_ + o] = acc + b_out[o];
}

// ----------------------------------------------------------------- launcher
extern "C" void kernel_launch(void* const* d_in, const int* in_sizes, int n_in,
                              void* d_out, int out_size, void* d_ws, size_t ws_size,
                              hipStream_t stream) {
    const int*   x     = (const int*)  d_in[0];
    const float* emb   = (const float*)d_in[1];
    const float* W_ih  = (const float*)d_in[2];
    const float* W_hh  = (const float*)d_in[3];
    const float* b_ih  = (const float*)d_in[4];
    const float* b_hh  = (const float*)d_in[5];
    const float* W_out = (const float*)d_in[6];
    const float* b_out = (const float*)d_in[7];
    float* out = (float*)d_out;

    char* ws = (char*)d_ws;
    _Float16* T2h   = (_Float16*)(ws + T_OFF);
    float*    hlast = (float*)(ws + HLAST_OFF);

    build_table<<<dim3(V_), dim3(256), 0, stream>>>(emb, W_ih, b_ih, b_hh, T2h);
    lstm_persistent<<<dim3(16), dim3(512), 0, stream>>>(x, W_hh, T2h, hlast);
    out_kernel<<<dim3(B_), dim3(O_), 0, stream>>>(hlast, W_out, b_out, out);
}